// Round 4
// baseline (91.630 us; speedup 1.0000x reference)
//
#include <hip/hip_runtime.h>
#include <math.h>

// Problem constants (B=8, T=1024, H=640, N_PHONE=230, N_PHONEME=96)
#define NH 640
#define NP 230
#define NM 96
#define NROWS 8192
#define MAXL 32
#define NSTEP 20            // K-steps of 32
#define NRT 512             // row-tiles of 16

// ws layout (byte offsets)
#define OFF_CNT  0
#define OFF_CSR  4096
#define OFF_B    65536      // wsB2: 20480 frags * 16 B = 327,680 B

typedef __bf16 bf16_t;
typedef bf16_t bf16x8 __attribute__((ext_vector_type(8)));
typedef float floatx4 __attribute__((ext_vector_type(4)));

// fp32 -> bf16 round-to-nearest-even
static __device__ __forceinline__ unsigned short f2b(float f) {
    unsigned u = __float_as_uint(f);
    u += 0x7fffu + ((u >> 16) & 1u);
    return (unsigned short)(u >> 16);
}

// ---------------- Prep: CSR build (blocks 0..23) + B retile (blocks 24..103)
// B frag g = (s*16+ct)*64+lane holds B^T[n=ct*16+(lane&15)][k=s*32+(lane>>4)*8+j], x8 bf16
__global__ __launch_bounds__(256)
void prep_kernel(const float* __restrict__ f2p,
                 const float* __restrict__ mapping,
                 int* __restrict__ cnt, int* __restrict__ csr,
                 unsigned short* __restrict__ wsB2) {
    const int b = blockIdx.x;
    const int tid = threadIdx.x;
    if (b < 24) {
        int wave = b * 4 + (tid >> 6);
        int lane = tid & 63;
        if (wave >= NM) return;
        int base = 0;
        #pragma unroll
        for (int c = 0; c < 4; ++c) {
            int p = c * 64 + lane;
            float v = (p < NP) ? mapping[wave * NP + p] : 0.0f;
            unsigned long long mask = __ballot(v > 0.0f);
            if (v > 0.0f) {
                int idx = base + __popcll(mask & ((1ull << lane) - 1ull));
                if (idx < MAXL) csr[wave * MAXL + idx] = p;
            }
            base += __popcll(mask);
        }
        if (lane == 0) cnt[wave] = base < MAXL ? base : MAXL;
    } else {
        int g = (b - 24) * 256 + tid;          // < 20480
        int m16  = g & 15;
        int quad = (g >> 4) & 3;
        int ct   = (g >> 6) & 15;
        int s    = g >> 10;
        int n = ct * 16 + m16;
        int k0 = s * 32 + quad * 8;
        unsigned short v[8];
        #pragma unroll
        for (int j = 0; j < 8; ++j)
            v[j] = (n < NP) ? f2b(f2p[(size_t)(k0 + j) * NP + n]) : (unsigned short)0;
        *(uint4*)(wsB2 + (size_t)g * 8) = *(const uint4*)v;
    }
}

// ---------------- Main: barrier-free MFMA K-loop.
// A direct from enc (fp32, inline cvt; a0+a1 jointly use full cache lines).
// B lane-linear fragment-major from ws (L2/L1-resident).
__global__ __launch_bounds__(256, 2)
void fused_phonetics_kernel(const float* __restrict__ enc,
                            const unsigned short* __restrict__ wsB2,
                            const int* __restrict__ cnt,
                            const int* __restrict__ csr,
                            float* __restrict__ out) {
    __shared__ float phone[16][257];

    const int tid  = threadIdx.x;
    const int lane = tid & 63;
    const int wv   = tid >> 6;
    const int m16  = lane & 15;
    const int quad = lane >> 4;
    const int rt   = blockIdx.x;
    const int row0 = rt * 16;

    floatx4 acc0 = {0.f,0.f,0.f,0.f}, acc1 = acc0, acc2 = acc0, acc3 = acc0;

    // A: lane holds A[m=row0+m16][k = s*32 + quad*8 + 0..7], cvt fp32->bf16
    const float* arow = enc + (size_t)(row0 + m16) * NH + quad * 8;
    // B: frag slot (s*16 + wv*4 + c)*64 + lane  (x8 bf16 = 16 B)
    const unsigned short* bptr = wsB2 + ((size_t)(wv * 4) * 64 + lane) * 8;

    #pragma unroll
    for (int s = 0; s < NSTEP; ++s) {
        float4 a0 = *(const float4*)(arow + s * 32);
        float4 a1 = *(const float4*)(arow + s * 32 + 4);
        uint4 b0 = *(const uint4*)(bptr + ((size_t)s * 16 + 0) * 64 * 8);
        uint4 b1 = *(const uint4*)(bptr + ((size_t)s * 16 + 1) * 64 * 8);
        uint4 b2 = *(const uint4*)(bptr + ((size_t)s * 16 + 2) * 64 * 8);
        uint4 b3 = *(const uint4*)(bptr + ((size_t)s * 16 + 3) * 64 * 8);
        union { unsigned short s16[8]; bf16x8 v; } au;
        au.s16[0] = f2b(a0.x); au.s16[1] = f2b(a0.y);
        au.s16[2] = f2b(a0.z); au.s16[3] = f2b(a0.w);
        au.s16[4] = f2b(a1.x); au.s16[5] = f2b(a1.y);
        au.s16[6] = f2b(a1.z); au.s16[7] = f2b(a1.w);
        bf16x8 af = au.v;
        acc0 = __builtin_amdgcn_mfma_f32_16x16x32_bf16(af, __builtin_bit_cast(bf16x8, b0), acc0, 0, 0, 0);
        acc1 = __builtin_amdgcn_mfma_f32_16x16x32_bf16(af, __builtin_bit_cast(bf16x8, b1), acc1, 0, 0, 0);
        acc2 = __builtin_amdgcn_mfma_f32_16x16x32_bf16(af, __builtin_bit_cast(bf16x8, b2), acc2, 0, 0, 0);
        acc3 = __builtin_amdgcn_mfma_f32_16x16x32_bf16(af, __builtin_bit_cast(bf16x8, b3), acc3, 0, 0, 0);
    }

    // C/D layout: col = lane&15, row = quad*4 + reg
    const float scale = 0.03952847075210474f;  // 1/sqrt(640)
    #pragma unroll
    for (int i = 0; i < 4; ++i) {
        int r = quad * 4 + i;
        phone[r][wv * 64 +  0 + m16] = acc0[i] * scale;
        phone[r][wv * 64 + 16 + m16] = acc1[i] * scale;
        phone[r][wv * 64 + 32 + m16] = acc2[i] * scale;
        phone[r][wv * 64 + 48 + m16] = acc3[i] * scale;
    }
    __syncthreads();

    // seg-max + log_softmax: 16 threads per row; thread handles m = l16 + 16j (j<6)
    const int r   = tid >> 4;
    const int l16 = tid & 15;
    float pmv[6];
    float mx = -INFINITY;
    #pragma unroll
    for (int j = 0; j < 6; ++j) {
        int m = l16 + j * 16;
        int c = cnt[m];
        const int* lst = csr + m * MAXL;
        float best = -INFINITY;
        for (int jj = 0; jj < c; ++jj) best = fmaxf(best, phone[r][lst[jj]]);
        pmv[j] = best;
        mx = fmaxf(mx, best);
    }
    #pragma unroll
    for (int d = 1; d < 16; d <<= 1) mx = fmaxf(mx, __shfl_xor(mx, d));
    float s = 0.f;
    #pragma unroll
    for (int j = 0; j < 6; ++j) s += __expf(pmv[j] - mx);
    #pragma unroll
    for (int d = 1; d < 16; d <<= 1) s += __shfl_xor(s, d);
    const float lse = mx + __logf(s);
    #pragma unroll
    for (int j = 0; j < 6; ++j)
        out[(size_t)(row0 + r) * NM + l16 + j * 16] = pmv[j] - lse;
}

extern "C" void kernel_launch(void* const* d_in, const int* in_sizes, int n_in,
                              void* d_out, int out_size, void* d_ws, size_t ws_size,
                              hipStream_t stream) {
    const float* enc     = (const float*)d_in[0];   // (8,1024,640) f32
    const float* f2p     = (const float*)d_in[1];   // (640,230) f32
    const float* mapping = (const float*)d_in[2];   // (96,230) f32
    float* out = (float*)d_out;                     // (8,1024,96) f32

    char* ws = (char*)d_ws;
    int* cnt = (int*)(ws + OFF_CNT);
    int* csr = (int*)(ws + OFF_CSR);
    unsigned short* wsB2 = (unsigned short*)(ws + OFF_B);

    prep_kernel<<<104, 256, 0, stream>>>(f2p, mapping, cnt, csr, wsB2);
    fused_phonetics_kernel<<<NRT, 256, 0, stream>>>(enc, wsB2, cnt, csr, out);
}

// Round 5
// 87.548 us; speedup vs baseline: 1.0466x; 1.0466x over previous
//
#include <hip/hip_runtime.h>
#include <math.h>

// Problem constants (B=8, T=1024, H=640, N_PHONE=230, N_PHONEME=96)
#define NH 640
#define NP 230
#define NM 96
#define NROWS 8192
#define MAXL 32
#define NSTEP 20            // K-steps of 32
#define MBLK 32             // rows per block
#define NBLOCKS (NROWS / MBLK)   // 256 -> 1 block/CU

// ws layout (byte offsets)
#define OFF_CNT  0
#define OFF_CSR  4096
#define OFF_B    65536      // wsB2: 20480 frags * 16 B = 327,680 B

typedef __bf16 bf16_t;
typedef bf16_t bf16x8 __attribute__((ext_vector_type(8)));
typedef float floatx4 __attribute__((ext_vector_type(4)));

// fp32 -> bf16 round-to-nearest-even
static __device__ __forceinline__ unsigned short f2b(float f) {
    unsigned u = __float_as_uint(f);
    u += 0x7fffu + ((u >> 16) & 1u);
    return (unsigned short)(u >> 16);
}

// ---------------- Prep: CSR build (blocks 0..23) + B retile (blocks 24..103)
// B frag g = (s*16+ct)*64+lane holds B^T[n=ct*16+(lane&15)][k=s*32+(lane>>4)*8+j]
__global__ __launch_bounds__(256)
void prep_kernel(const float* __restrict__ f2p,
                 const float* __restrict__ mapping,
                 int* __restrict__ cnt, int* __restrict__ csr,
                 unsigned short* __restrict__ wsB2) {
    const int b = blockIdx.x;
    const int tid = threadIdx.x;
    if (b < 24) {
        int wave = b * 4 + (tid >> 6);
        int lane = tid & 63;
        if (wave >= NM) return;
        int base = 0;
        #pragma unroll
        for (int c = 0; c < 4; ++c) {
            int p = c * 64 + lane;
            float v = (p < NP) ? mapping[wave * NP + p] : 0.0f;
            unsigned long long mask = __ballot(v > 0.0f);
            if (v > 0.0f) {
                int idx = base + __popcll(mask & ((1ull << lane) - 1ull));
                if (idx < MAXL) csr[wave * MAXL + idx] = p;
            }
            base += __popcll(mask);
        }
        if (lane == 0) cnt[wave] = base < MAXL ? base : MAXL;
    } else {
        int g = (b - 24) * 256 + tid;          // < 20480
        int m16  = g & 15;
        int quad = (g >> 4) & 3;
        int ct   = (g >> 6) & 15;
        int s    = g >> 10;
        int n = ct * 16 + m16;
        int k0 = s * 32 + quad * 8;
        unsigned short v[8];
        #pragma unroll
        for (int j = 0; j < 8; ++j)
            v[j] = (n < NP) ? f2b(f2p[(size_t)(k0 + j) * NP + n]) : (unsigned short)0;
        *(uint4*)(wsB2 + (size_t)g * 8) = *(const uint4*)v;
    }
}

// ---------------- Main: in-kernel A retile (coalesced global -> frag-major LDS),
// barrier-free MFMA K-loop (A ds_read_b128 lane-linear, B lane-linear from L2),
// fused seg-max + log_softmax. 512 thr (8 waves): wave = rh (row half) x cq (col quad).
__global__ __launch_bounds__(512, 1)
void fused_phonetics_kernel(const float* __restrict__ enc,
                            const unsigned short* __restrict__ wsB2,
                            const int* __restrict__ cnt,
                            const int* __restrict__ csr,
                            float* __restrict__ out) {
    // A frags: slot f = (s*2 + rh)*64 + lane, 8 bf16 each -> 2560*16 = 40960 B.
    // Reused as phone[32][257] floats (32896 B) in the epilogue.
    __shared__ __align__(16) unsigned short sA[2560 * 8];
    float (*phone)[257] = (float (*)[257])sA;

    const int tid  = threadIdx.x;
    const int lane = tid & 63;
    const int wv   = tid >> 6;          // 0..7
    const int m16  = lane & 15;
    const int quad = lane >> 4;
    const int rh   = wv & 1;            // row half (16 rows)
    const int cq   = wv >> 1;           // col quad (64 cols)
    const int row0 = blockIdx.x * MBLK;

    // ---- Stage A: 32 rows x 640 k, fp32 coalesced -> bf16 frag-major LDS
    // iter i: thread reads float4 at flat F = i*2048 + tid*4 (perfectly coalesced)
    #pragma unroll
    for (int i = 0; i < 10; ++i) {
        int F = i * 2048 + tid * 4;
        int row = F / 640;
        int k   = F - row * 640;
        float4 a = *(const float4*)(enc + (size_t)row0 * NH + F);
        int s  = k >> 5;
        int q  = (k & 31) >> 3;
        int j0 = k & 7;                  // 0 or 4
        unsigned short v[4];
        v[0] = f2b(a.x); v[1] = f2b(a.y); v[2] = f2b(a.z); v[3] = f2b(a.w);
        int soff = ((s * 2 + (row >> 4)) * 64 + q * 16 + (row & 15)) * 8 + j0;
        *(uint2*)(sA + soff) = *(const uint2*)v;
    }
    __syncthreads();

    floatx4 acc0 = {0.f,0.f,0.f,0.f}, acc1 = acc0, acc2 = acc0, acc3 = acc0;

    const unsigned short* aptr = sA + ((size_t)rh * 64 + lane) * 8;
    const unsigned short* bptr = wsB2 + ((size_t)(cq * 4) * 64 + lane) * 8;

    #pragma unroll
    for (int s = 0; s < NSTEP; ++s) {
        uint4 a  = *(const uint4*)(aptr + (size_t)(s * 2) * 64 * 8);
        uint4 b0 = *(const uint4*)(bptr + ((size_t)s * 16 + 0) * 64 * 8);
        uint4 b1 = *(const uint4*)(bptr + ((size_t)s * 16 + 1) * 64 * 8);
        uint4 b2 = *(const uint4*)(bptr + ((size_t)s * 16 + 2) * 64 * 8);
        uint4 b3 = *(const uint4*)(bptr + ((size_t)s * 16 + 3) * 64 * 8);
        bf16x8 af = __builtin_bit_cast(bf16x8, a);
        acc0 = __builtin_amdgcn_mfma_f32_16x16x32_bf16(af, __builtin_bit_cast(bf16x8, b0), acc0, 0, 0, 0);
        acc1 = __builtin_amdgcn_mfma_f32_16x16x32_bf16(af, __builtin_bit_cast(bf16x8, b1), acc1, 0, 0, 0);
        acc2 = __builtin_amdgcn_mfma_f32_16x16x32_bf16(af, __builtin_bit_cast(bf16x8, b2), acc2, 0, 0, 0);
        acc3 = __builtin_amdgcn_mfma_f32_16x16x32_bf16(af, __builtin_bit_cast(bf16x8, b3), acc3, 0, 0, 0);
    }

    __syncthreads();   // A-LDS fully consumed; safe to overwrite with phone[][]

    // C/D layout: col = lane&15, row = quad*4 + reg
    const float scale = 0.03952847075210474f;  // 1/sqrt(640)
    #pragma unroll
    for (int i = 0; i < 4; ++i) {
        int r = rh * 16 + quad * 4 + i;
        phone[r][cq * 64 +  0 + m16] = acc0[i] * scale;
        phone[r][cq * 64 + 16 + m16] = acc1[i] * scale;
        phone[r][cq * 64 + 32 + m16] = acc2[i] * scale;
        phone[r][cq * 64 + 48 + m16] = acc3[i] * scale;
    }
    __syncthreads();

    // seg-max + log_softmax: 16 threads per row (512 = 32 rows x 16)
    const int r   = tid >> 4;
    const int l16 = tid & 15;
    float pmv[6];
    float mx = -INFINITY;
    #pragma unroll
    for (int j = 0; j < 6; ++j) {
        int m = l16 + j * 16;
        int c = cnt[m];
        const int* lst = csr + m * MAXL;
        float best = -INFINITY;
        for (int jj = 0; jj < c; ++jj) best = fmaxf(best, phone[r][lst[jj]]);
        pmv[j] = best;
        mx = fmaxf(mx, best);
    }
    #pragma unroll
    for (int d = 1; d < 16; d <<= 1) mx = fmaxf(mx, __shfl_xor(mx, d));
    float s = 0.f;
    #pragma unroll
    for (int j = 0; j < 6; ++j) s += __expf(pmv[j] - mx);
    #pragma unroll
    for (int d = 1; d < 16; d <<= 1) s += __shfl_xor(s, d);
    const float lse = mx + __logf(s);
    #pragma unroll
    for (int j = 0; j < 6; ++j)
        out[(size_t)(row0 + r) * NM + l16 + j * 16] = pmv[j] - lse;
}

extern "C" void kernel_launch(void* const* d_in, const int* in_sizes, int n_in,
                              void* d_out, int out_size, void* d_ws, size_t ws_size,
                              hipStream_t stream) {
    const float* enc     = (const float*)d_in[0];   // (8,1024,640) f32
    const float* f2p     = (const float*)d_in[1];   // (640,230) f32
    const float* mapping = (const float*)d_in[2];   // (96,230) f32
    float* out = (float*)d_out;                     // (8,1024,96) f32

    char* ws = (char*)d_ws;
    int* cnt = (int*)(ws + OFF_CNT);
    int* csr = (int*)(ws + OFF_CSR);
    unsigned short* wsB2 = (unsigned short*)(ws + OFF_B);

    prep_kernel<<<104, 256, 0, stream>>>(f2p, mapping, cnt, csr, wsB2);
    fused_phonetics_kernel<<<NBLOCKS, 512, 0, stream>>>(enc, wsB2, cnt, csr, out);
}